// Round 6
// baseline (32.886 us; speedup 1.0000x reference)
//
#include <hip/hip_runtime.h>
#include <hip/hip_cooperative_groups.h>
#include <math.h>

namespace cg = cooperative_groups;

#define DIM 4096
#define BATCH 8192
#define NB 8                 // blocks; each handles BATCH/NB = 1024 betas (1/thread)
#define NT 1024
#define NWAVES (NT / 64)

// Cooperative single-dispatch kernel, NB blocks x NT threads.
// Each block independently: loads all lambdas/gammas (concurrent; L3 dedups),
// builds the full 4-series f32 prefix table in its OWN LDS (round-3 scan),
// joins its 1024-beta slice (1 gather/thread), block-reduces to 4 floats,
// writes a float4 slot to d_ws. grid.sync(). Block 0 sums NB slots + epilogue.
// No ws-state init needed: slots are plain-written every call before being read.
__global__ __launch_bounds__(NT)
void calc_kernel(const float* __restrict__ betas,
                 const float* __restrict__ lambdas,
                 const float* __restrict__ gammas,
                 float4* __restrict__ slots,
                 float* __restrict__ out)
{
    __shared__ float4 s4[DIM];        // 64 KB prefix table (per block)
    __shared__ float4 ovl4[NWAVES];
    __shared__ float4 red4[NWAVES];

    const int t = threadIdx.x;
    const int lane = t & 63;
    const int wave = t >> 6;
    const int j0 = t * 4;
    const int blk = blockIdx.x;

    // ---- all global loads up front ----
    const float4 la4 = *reinterpret_cast<const float4*>(lambdas + j0);
    const float4 ga4 = *reinterpret_cast<const float4*>(gammas + j0);
    const float beta = betas[blk * NT + t];   // one beta per thread

    // ---- K + logK (exact IEEE f32 op sequence for floor fidelity) ----
    float lamb = 1.0f - 1.0f / beta;
    float kf   = 1.0f / (1.0f - lamb) - 1.0f;
    int K = (int)floorf(kf);
    K = min(max(K, 1), DIM - 1);
    float lk = __logf((float)K);

    // ---- per-element series values ----
    float las[4] = { la4.x, la4.y, la4.z, la4.w };
    float gas[4] = { ga4.x, ga4.y, ga4.z, ga4.w };
    float e[4][4];
    float tot0 = 0.f, tot1 = 0.f, tot2 = 0.f, tot3 = 0.f;
    #pragma unroll
    for (int i = 0; i < 4; ++i) {
        float g = gas[i];
        float l = las[i];
        float v0 = g;
        float v1 = g * __logf((float)(j0 + i + 1));
        float v2 = g * __logf(l);
        float v3 = g * __logf(1.0f - l);     // lam in (0.05,0.95): safe as log
        e[i][0] = v0; e[i][1] = v1; e[i][2] = v2; e[i][3] = v3;
        tot0 += v0; tot1 += v1; tot2 += v2; tot3 += v3;
    }

    // ---- wave-level inclusive scan (f32 shfl, width 64) ----
    float i0 = tot0, i1 = tot1, i2 = tot2, i3 = tot3;
    #pragma unroll
    for (int off = 1; off < 64; off <<= 1) {
        float y0 = __shfl_up(i0, off, 64);
        float y1 = __shfl_up(i1, off, 64);
        float y2 = __shfl_up(i2, off, 64);
        float y3 = __shfl_up(i3, off, 64);
        if (lane >= off) { i0 += y0; i1 += y1; i2 += y2; i3 += y3; }
    }
    if (lane == 63) ovl4[wave] = make_float4(i0, i1, i2, i3);
    __syncthreads();

    // cross-wave base: sum preceding wave totals (broadcast b128 reads)
    float b0 = i0 - tot0, b1 = i1 - tot1, b2 = i2 - tot2, b3 = i3 - tot3;
    for (int w = 0; w < wave; ++w) {
        float4 o = ovl4[w];
        b0 += o.x; b1 += o.y; b2 += o.z; b3 += o.w;
    }
    #pragma unroll
    for (int i = 0; i < 4; ++i) {
        b0 += e[i][0]; b1 += e[i][1]; b2 += e[i][2]; b3 += e[i][3];
        s4[j0 + i] = make_float4(b0, b1, b2, b3);
    }
    __syncthreads();

    // ---- join: one gather per thread ----
    float4 p = s4[K - 1];                // inclusive prefix at K-1 == sum_{j<K}
    float a0 = lk * p.x - p.y;           // ixt contribution
    float a1 = p.x;                      // n_I
    float a2 = p.z;                      // S_lambda
    float a3 = p.w;                      // S_lambda_comp

    // ---- block reduce ----
    #pragma unroll
    for (int off = 32; off > 0; off >>= 1) {
        a0 += __shfl_down(a0, off, 64);
        a1 += __shfl_down(a1, off, 64);
        a2 += __shfl_down(a2, off, 64);
        a3 += __shfl_down(a3, off, 64);
    }
    if (lane == 0) red4[wave] = make_float4(a0, a1, a2, a3);
    __syncthreads();
    if (t == 0) {
        float s0 = 0.f, s1 = 0.f, s2 = 0.f, s3 = 0.f;
        #pragma unroll
        for (int w = 0; w < NWAVES; ++w) {
            float4 rv = red4[w];
            s0 += rv.x; s1 += rv.y; s2 += rv.z; s3 += rv.w;
        }
        slots[blk] = make_float4(s0, s1, s2, s3);
    }

    cg::this_grid().sync();              // runtime-managed grid barrier

    if (blk == 0 && t == 0) {
        __threadfence();                 // belt-and-braces acquire
        float ixt = 0.f, nI = 0.f, Sl = 0.f, Sl1 = 0.f;
        #pragma unroll
        for (int i = 0; i < NB; ++i) {
            float4 v = slots[i];
            ixt += v.x; nI += v.y; Sl += v.z; Sl1 += v.w;
        }
        float inv_nI = 1.0f / nI;
        float gm_term  = __expf(Sl  * inv_nI);
        float gm_comp  = __expf(Sl1 * inv_nI);
        float exp_term = __expf(2.0f * ixt * inv_nI);
        float log_term = -nI * 0.5f * __logf(gm_comp + exp_term * gm_term);
        float rhs = 1.0f - (ixt + log_term);   // IXY = 1
        float l1  = 1.0f - ixt * 0.1f;         // HX = 10
        if (l1 < 0.0f) l1 = fabsf(l1) * 20.0f;
        out[0] = rhs;
        out[1] = l1 * l1;                      // C=1, ALPHA=2
    }
}

extern "C" void kernel_launch(void* const* d_in, const int* in_sizes, int n_in,
                              void* d_out, int out_size, void* d_ws, size_t ws_size,
                              hipStream_t stream) {
    const float* betas   = (const float*)d_in[0];
    const float* lambdas = (const float*)d_in[1];
    const float* gammas  = (const float*)d_in[2];
    float4* slots = (float4*)d_ws;
    float*  out   = (float*)d_out;
    void* args[] = { (void*)&betas, (void*)&lambdas, (void*)&gammas,
                     (void*)&slots, (void*)&out };
    hipLaunchCooperativeKernel((const void*)calc_kernel, dim3(NB), dim3(NT),
                               args, 0, stream);
}

// Round 7
// 10.618 us; speedup vs baseline: 3.0971x; 3.0971x over previous
//
#include <hip/hip_runtime.h>
#include <math.h>

#define DIM 4096
#define BATCH 8192
#define NT 1024
#define NWAVES (NT / 64)
#define RPT (BATCH / NT)   // betas per thread = 8

// DPP-based wave64 inclusive scan step: x += dpp_shifted(x), on the VALU pipe
// (no ds_bpermute). CDNA keeps GCN row_shr / row_bcast15 / row_bcast31.
template <int CTRL, int ROWMASK>
__device__ __forceinline__ float dpp_add(float x) {
    int t = __builtin_amdgcn_update_dpp(0, __float_as_int(x),
                                        CTRL, ROWMASK, 0xf, true);
    return x + __int_as_float(t);
}

// Kogge-Stone inclusive scan across 64 lanes: row_shr 1,2,4,8 within 16-lane
// rows, then row_bcast15 (rows 1,3) and row_bcast31 (rows 2,3).
__device__ __forceinline__ float wave_scan(float x) {
    x = dpp_add<0x111, 0xf>(x);   // row_shr:1
    x = dpp_add<0x112, 0xf>(x);   // row_shr:2
    x = dpp_add<0x114, 0xf>(x);   // row_shr:4
    x = dpp_add<0x118, 0xf>(x);   // row_shr:8
    x = dpp_add<0x142, 0xa>(x);   // row_bcast:15 -> rows 1,3
    x = dpp_add<0x143, 0xc>(x);   // row_bcast:31 -> rows 2,3
    return x;                     // lane 63 = wave total
}

// Single-block fused kernel (round-3 structure, divide-free K, DPP scans).
__global__ __launch_bounds__(NT)
void calc_kernel(const float* __restrict__ betas,
                 const float* __restrict__ lambdas,
                 const float* __restrict__ gammas,
                 float* __restrict__ out)
{
    __shared__ float4 s4[DIM];        // 64 KB prefix table
    __shared__ float4 ovl4[NWAVES];   // per-wave totals of the 4 series
    __shared__ float4 red4[NWAVES];   // per-wave phase-2 partial sums

    const int t = threadIdx.x;
    const int lane = t & 63;
    const int wave = t >> 6;
    const int j0 = t * 4;

    // ---- all global loads up front (hide cold-HBM latency under math) ----
    const float4 la4 = *reinterpret_cast<const float4*>(lambdas + j0);
    const float4 ga4 = *reinterpret_cast<const float4*>(gammas + j0);
    const float4* b4p = reinterpret_cast<const float4*>(betas);
    const float4 bv0 = b4p[t];
    const float4 bv1 = b4p[NT + t];

    // ---- K + logK per beta, divide-free ----
    // reference kf = f32roundtrip(beta)-1 = beta-1 within ~3 ulp; floor can
    // differ only for betas ~1e-3 from an integer (few per 8192, each worth
    // ~0.25 on ixt vs ~20 budget).
    float bet[RPT] = { bv0.x, bv0.y, bv0.z, bv0.w, bv1.x, bv1.y, bv1.z, bv1.w };
    int   K[RPT];
    float lk[RPT];
    #pragma unroll
    for (int r = 0; r < RPT; ++r) {
        int k = (int)floorf(bet[r] - 1.0f);
        k = min(max(k, 1), DIM - 1);
        K[r]  = k;
        lk[r] = __logf((float)k);
    }

    // ---- per-element series values ----
    float las[4] = { la4.x, la4.y, la4.z, la4.w };
    float gas[4] = { ga4.x, ga4.y, ga4.z, ga4.w };
    float e[4][4];
    float tot0 = 0.f, tot1 = 0.f, tot2 = 0.f, tot3 = 0.f;
    #pragma unroll
    for (int i = 0; i < 4; ++i) {
        float g = gas[i];
        float l = las[i];
        float v0 = g;
        float v1 = g * __logf((float)(j0 + i + 1));
        float v2 = g * __logf(l);
        float v3 = g * __logf(1.0f - l);     // lam in (0.05,0.95): safe as log
        e[i][0] = v0; e[i][1] = v1; e[i][2] = v2; e[i][3] = v3;
        tot0 += v0; tot1 += v1; tot2 += v2; tot3 += v3;
    }

    // ---- wave-level inclusive scan of per-thread totals (DPP, VALU pipe) ----
    float i0 = wave_scan(tot0);
    float i1 = wave_scan(tot1);
    float i2 = wave_scan(tot2);
    float i3 = wave_scan(tot3);
    if (lane == 63) ovl4[wave] = make_float4(i0, i1, i2, i3);
    __syncthreads();

    // cross-wave base: sum preceding wave totals (broadcast b128 reads)
    float b0 = i0 - tot0, b1 = i1 - tot1, b2 = i2 - tot2, b3 = i3 - tot3;
    for (int w = 0; w < wave; ++w) {
        float4 o = ovl4[w];
        b0 += o.x; b1 += o.y; b2 += o.z; b3 += o.w;
    }
    #pragma unroll
    for (int i = 0; i < 4; ++i) {
        b0 += e[i][0]; b1 += e[i][1]; b2 += e[i][2]; b3 += e[i][3];
        s4[j0 + i] = make_float4(b0, b1, b2, b3);
    }
    __syncthreads();

    // ---- per-beta gathers ----
    float a0 = 0.f, a1 = 0.f, a2 = 0.f, a3 = 0.f;
    #pragma unroll
    for (int r = 0; r < RPT; ++r) {
        float4 p = s4[K[r] - 1];       // inclusive prefix at K-1 == sum_{j<K}
        a0 += lk[r] * p.x - p.y;       // ixt contribution
        a1 += p.x;                     // n_I
        a2 += p.z;                     // S_lambda
        a3 += p.w;                     // S_lambda_comp
    }

    // ---- per-wave reduce via DPP scan (lane 63 holds total) ----
    a0 = wave_scan(a0);
    a1 = wave_scan(a1);
    a2 = wave_scan(a2);
    a3 = wave_scan(a3);
    if (lane == 63) red4[wave] = make_float4(a0, a1, a2, a3);
    __syncthreads();

    if (t == 0) {
        float s0 = 0.f, s1 = 0.f, s2 = 0.f, s3 = 0.f;
        #pragma unroll
        for (int w = 0; w < NWAVES; ++w) {
            float4 rv = red4[w];
            s0 += rv.x; s1 += rv.y; s2 += rv.z; s3 += rv.w;
        }
        float ixt = s0;
        float nI  = s1;
        float inv_nI = 1.0f / nI;
        float gm_term  = __expf(s2 * inv_nI);
        float gm_comp  = __expf(s3 * inv_nI);
        float exp_term = __expf(2.0f * ixt * inv_nI);
        float log_term = -nI * 0.5f * __logf(gm_comp + exp_term * gm_term);
        float rhs = 1.0f - (ixt + log_term);   // IXY = 1
        float l1  = 1.0f - ixt * 0.1f;         // HX = 10
        if (l1 < 0.0f) l1 = fabsf(l1) * 20.0f;
        out[0] = rhs;
        out[1] = l1 * l1;                      // C=1, ALPHA=2
    }
}

extern "C" void kernel_launch(void* const* d_in, const int* in_sizes, int n_in,
                              void* d_out, int out_size, void* d_ws, size_t ws_size,
                              hipStream_t stream) {
    const float* betas   = (const float*)d_in[0];
    const float* lambdas = (const float*)d_in[1];
    const float* gammas  = (const float*)d_in[2];
    calc_kernel<<<1, NT, 0, stream>>>(betas, lambdas, gammas, (float*)d_out);
}